// Round 1
// baseline (575.626 us; speedup 1.0000x reference)
//
#include <hip/hip_runtime.h>

#define TS 64
#define KS 16

__device__ __forceinline__ float lrelu(float v) { return v >= 0.f ? v : 0.01f * v; }

// ---------------------------------------------------------------------------
// C[i][j] = sum_k A[i][k] * B[k][j]   (all row-major, M x K, K x N)
// grid: (N/TS, M/TS), block 256
// ---------------------------------------------------------------------------
__global__ __launch_bounds__(256) void k_gemm_nn(const float* __restrict__ A,
                                                 const float* __restrict__ B,
                                                 float* __restrict__ C,
                                                 int M, int N, int K) {
    __shared__ float As[TS][KS + 1];  // As[i][k] padded
    __shared__ float Bs[KS][TS];      // Bs[k][j]
    int tid = threadIdx.x;
    int tx = tid & 15, ty = tid >> 4;
    int i0 = blockIdx.y * TS, j0 = blockIdx.x * TS;
    float acc[4][4] = {};
    for (int k0 = 0; k0 < K; k0 += KS) {
        {
            int c = tid & 15, r0 = tid >> 4;
#pragma unroll
            for (int l = 0; l < 4; ++l) {
                int r = r0 + l * 16;
                As[r][c] = A[(i0 + r) * K + k0 + c];
            }
        }
        {
            int j = tid & 63, r0 = tid >> 6;
#pragma unroll
            for (int l = 0; l < 4; ++l) {
                int r = r0 + l * 4;
                Bs[r][j] = B[(k0 + r) * N + j0 + j];
            }
        }
        __syncthreads();
#pragma unroll
        for (int kk = 0; kk < KS; ++kk) {
            float4 b4 = *(const float4*)&Bs[kk][tx * 4];
#pragma unroll
            for (int i = 0; i < 4; ++i) {
                float a = As[ty * 4 + i][kk];
                acc[i][0] += a * b4.x; acc[i][1] += a * b4.y;
                acc[i][2] += a * b4.z; acc[i][3] += a * b4.w;
            }
        }
        __syncthreads();
    }
#pragma unroll
    for (int i = 0; i < 4; ++i) {
        float4 v = {acc[i][0], acc[i][1], acc[i][2], acc[i][3]};
        *(float4*)&C[(i0 + ty * 4 + i) * N + j0 + tx * 4] = v;
    }
}

// ---------------------------------------------------------------------------
// Stage A: Out[b][t][k][o] = sum_c Wmat[o][c] * In_k[b][c][t]
// grid: (B*T/TS, C/TS, 9)  z = wsel*3 + kin ; block 256
// ---------------------------------------------------------------------------
__global__ __launch_bounds__(256) void k_stageA(
    const float* __restrict__ out1, const float* __restrict__ out2,
    const float* __restrict__ out3, const float* __restrict__ theta_w,
    const float* __restrict__ phi_w, const float* __restrict__ wg_w,
    float* __restrict__ Th, float* __restrict__ Ph, float* __restrict__ Wg) {
    const int Cc = 512, T = 128;
    int wsel = blockIdx.z / 3, kin = blockIdx.z % 3;
    const float* W = (wsel == 0) ? theta_w : ((wsel == 1) ? phi_w : wg_w);
    const float* In = (kin == 0) ? out1 : ((kin == 1) ? out2 : out3);
    float* Out = (wsel == 0) ? Th : ((wsel == 1) ? Ph : Wg);

    int col0 = blockIdx.x * TS;
    int b = col0 >> 7, t0 = col0 & 127;
    int o0 = blockIdx.y * TS;

    __shared__ float As[TS][KS + 1];  // As[o][k]
    __shared__ float Bs[KS][TS];      // Bs[k][t]
    int tid = threadIdx.x;
    int tx = tid & 15, ty = tid >> 4;
    float acc[4][4] = {};  // [i=o][j=t]

    for (int k0 = 0; k0 < 512; k0 += KS) {
        {
            int c = tid & 15, r0 = tid >> 4;
#pragma unroll
            for (int l = 0; l < 4; ++l) {
                int r = r0 + l * 16;
                As[r][c] = W[(o0 + r) * Cc + k0 + c];
            }
        }
        {
            int j = tid & 63, r0 = tid >> 6;
#pragma unroll
            for (int l = 0; l < 4; ++l) {
                int r = r0 + l * 4;
                Bs[r][j] = In[(b * Cc + k0 + r) * T + t0 + j];
            }
        }
        __syncthreads();
#pragma unroll
        for (int kk = 0; kk < KS; ++kk) {
            float4 b4 = *(const float4*)&Bs[kk][tx * 4];
#pragma unroll
            for (int i = 0; i < 4; ++i) {
                float a = As[ty * 4 + i][kk];
                acc[i][0] += a * b4.x; acc[i][1] += a * b4.y;
                acc[i][2] += a * b4.z; acc[i][3] += a * b4.w;
            }
        }
        __syncthreads();
    }
#pragma unroll
    for (int jj = 0; jj < 4; ++jj) {
        int t = t0 + tx * 4 + jj;
        float4 v = {acc[0][jj], acc[1][jj], acc[2][jj], acc[3][jj]};
        *(float4*)&Out[(((b * T + t) * 3 + kin) << 9) + o0 + ty * 4] = v;
    }
}

// ---------------------------------------------------------------------------
// Stage B: per (b,t): f = Theta_win^T Phi_win (24x24, K=512), softmax rows,
//          pooled[o] = max_n ( sum_m P[n][m]*WG_win[o][m] + W_b[o] + X_win[o][n] )
// grid: B*T blocks of 512 threads
// ---------------------------------------------------------------------------
__global__ __launch_bounds__(512) void k_stageB(
    const float* __restrict__ out1, const float* __restrict__ out2,
    const float* __restrict__ out3, const float* __restrict__ Th,
    const float* __restrict__ Ph, const float* __restrict__ Wg,
    const float* __restrict__ W_b, float* __restrict__ Pl) {
    const int Cc = 512, T = 128, Bb = 16;
    int bid = blockIdx.x;
    int b = bid >> 7, t = bid & 127;
    int tid = threadIdx.x;

    __shared__ float Phw[24][512];
    __shared__ float Pm[24][25];

    // stage Phi window into LDS (zeros for t' < 0)
    for (int idx = tid; idx < 24 * 128; idx += 512) {
        int n = idx >> 7, o4 = idx & 127;
        int j = n / 3, k = n % 3, tp = t - 7 + j;
        float4 v = {0.f, 0.f, 0.f, 0.f};
        if (tp >= 0) v = *(const float4*)&Ph[(((b * T + tp) * 3 + k) << 9) + o4 * 4];
        *(float4*)&Phw[n][o4 * 4] = v;
    }
    __syncthreads();

    // f[n][m]: one wave per row-group, lanes split the 512-dot
    int wave = tid >> 6, lane = tid & 63;
    for (int n = wave; n < 24; n += 8) {
        int j = n / 3, k = n % 3, tp = t - 7 + j;
        float4 a1 = {0, 0, 0, 0}, a2 = {0, 0, 0, 0};
        if (tp >= 0) {
            const float* base = &Th[(((b * T + tp) * 3 + k) << 9)];
            a1 = *(const float4*)&base[lane * 4];
            a2 = *(const float4*)&base[256 + lane * 4];
        }
        for (int m = 0; m < 24; ++m) {
            float4 b1 = *(const float4*)&Phw[m][lane * 4];
            float4 b2 = *(const float4*)&Phw[m][256 + lane * 4];
            float s = a1.x * b1.x + a1.y * b1.y + a1.z * b1.z + a1.w * b1.w +
                      a2.x * b2.x + a2.y * b2.y + a2.z * b2.z + a2.w * b2.w;
#pragma unroll
            for (int off = 32; off; off >>= 1) s += __shfl_down(s, off, 64);
            if (lane == 0) Pm[n][m] = s;
        }
    }
    __syncthreads();

    // softmax rows (over m)
    if (tid < 24) {
        float mx = -1e30f;
#pragma unroll
        for (int m = 0; m < 24; ++m) mx = fmaxf(mx, Pm[tid][m]);
        float e[24], sum = 0.f;
#pragma unroll
        for (int m = 0; m < 24; ++m) { e[m] = __expf(Pm[tid][m] - mx); sum += e[m]; }
        float inv = 1.0f / sum;
#pragma unroll
        for (int m = 0; m < 24; ++m) Pm[tid][m] = e[m] * inv;
    }
    __syncthreads();

    // phase 2: one o per thread
    int o = tid;
    float wg[24], xw[24];
#pragma unroll
    for (int m = 0; m < 24; ++m) {
        int j = m / 3, k = m % 3, tp = t - 7 + j;
        wg[m] = (tp >= 0) ? Wg[(((b * T + tp) * 3 + k) << 9) + o] : 0.f;
        const float* xin = (k == 0) ? out1 : ((k == 1) ? out2 : out3);
        xw[m] = (tp >= 0) ? xin[(b * Cc + o) * T + tp] : 0.f;
    }
    float wb = W_b[o];
    float pooled = -1e30f;
    for (int n = 0; n < 24; ++n) {
        float s = 0.f;
#pragma unroll
        for (int m = 0; m < 24; ++m) s += Pm[n][m] * wg[m];
        s += wb + xw[n];
        pooled = fmaxf(pooled, s);
    }
    Pl[((t * Bb + b) << 9) + o] = pooled;
}

// ---------------------------------------------------------------------------
// C[r][o] = lrelu( sum_c A[r][c] * W[o][c] )   A: MxK row-major, W: NxK row-major
// grid: (M/TS, N/TS), block 256
// ---------------------------------------------------------------------------
__global__ __launch_bounds__(256) void k_gemm_nt_act(const float* __restrict__ A,
                                                     const float* __restrict__ W,
                                                     float* __restrict__ C,
                                                     int M, int N, int K) {
    __shared__ float As[TS][KS + 1];
    __shared__ float Ws[TS][KS + 1];
    int tid = threadIdx.x;
    int tx = tid & 15, ty = tid >> 4;
    int i0 = blockIdx.x * TS;  // rows
    int j0 = blockIdx.y * TS;  // out cols
    float acc[4][4] = {};
    for (int k0 = 0; k0 < K; k0 += KS) {
        int c = tid & 15, r0 = tid >> 4;
#pragma unroll
        for (int l = 0; l < 4; ++l) {
            int r = r0 + l * 16;
            As[r][c] = A[(i0 + r) * K + k0 + c];
            Ws[r][c] = W[(j0 + r) * K + k0 + c];
        }
        __syncthreads();
#pragma unroll
        for (int kk = 0; kk < KS; ++kk) {
            float a[4], w[4];
#pragma unroll
            for (int i = 0; i < 4; ++i) a[i] = As[ty * 4 + i][kk];
#pragma unroll
            for (int j = 0; j < 4; ++j) w[j] = Ws[tx * 4 + j][kk];
#pragma unroll
            for (int i = 0; i < 4; ++i)
#pragma unroll
                for (int j = 0; j < 4; ++j) acc[i][j] += a[i] * w[j];
        }
        __syncthreads();
    }
#pragma unroll
    for (int i = 0; i < 4; ++i) {
        float4 v = {lrelu(acc[i][0]), lrelu(acc[i][1]), lrelu(acc[i][2]), lrelu(acc[i][3])};
        *(float4*)&C[(i0 + ty * 4 + i) * N + j0 + tx * 4] = v;
    }
}

// ---------------------------------------------------------------------------
// out[r] = lrelu( sum_c H[r][c]*p3w[c] + p3b )   one wave per row
// grid: M/4 blocks of 256
// ---------------------------------------------------------------------------
__global__ __launch_bounds__(256) void k_final(const float* __restrict__ H,
                                               const float* __restrict__ p3w,
                                               const float* __restrict__ p3b,
                                               float* __restrict__ out) {
    int r = blockIdx.x * 4 + (threadIdx.x >> 6);
    int lane = threadIdx.x & 63;
    const float4* h4 = (const float4*)&H[r << 9];
    const float4* w4 = (const float4*)p3w;
    float4 a1 = h4[lane], a2 = h4[lane + 64];
    float4 b1 = w4[lane], b2 = w4[lane + 64];
    float s = a1.x * b1.x + a1.y * b1.y + a1.z * b1.z + a1.w * b1.w +
              a2.x * b2.x + a2.y * b2.y + a2.z * b2.z + a2.w * b2.w;
#pragma unroll
    for (int off = 32; off; off >>= 1) s += __shfl_down(s, off, 64);
    if (lane == 0) out[r] = lrelu(s + p3b[0]);
}

extern "C" void kernel_launch(void* const* d_in, const int* in_sizes, int n_in,
                              void* d_out, int out_size, void* d_ws, size_t ws_size,
                              hipStream_t stream) {
    const float* out1 = (const float*)d_in[0];
    const float* out2 = (const float*)d_in[1];
    const float* out3 = (const float*)d_in[2];
    const float* theta_w = (const float*)d_in[3];
    const float* phi_w = (const float*)d_in[4];
    const float* g_w = (const float*)d_in[5];
    const float* W_w = (const float*)d_in[6];
    const float* W_b = (const float*)d_in[7];
    const float* p1_w = (const float*)d_in[8];
    const float* p2_w = (const float*)d_in[9];
    const float* p3_w = (const float*)d_in[10];
    const float* p3_b = (const float*)d_in[11];
    float* outp = (float*)d_out;

    // workspace layout (floats)
    float* ws = (float*)d_ws;
    float* Wg_w = ws;                  // 512*512
    float* Th = Wg_w + 512 * 512;      // 16*128*3*512
    float* Ph = Th + 16 * 128 * 3 * 512;
    float* Wg = Ph + 16 * 128 * 3 * 512;
    float* Pl = Wg + 16 * 128 * 3 * 512;  // 2048*512
    float* h1 = Th;  // reuse (Th dead after stage B)
    float* h2 = Ph;  // reuse

    // Wg_w = W_w @ g_w
    k_gemm_nn<<<dim3(8, 8), 256, 0, stream>>>(W_w, g_w, Wg_w, 512, 512, 512);
    // Theta / Phi / WG
    k_stageA<<<dim3(32, 8, 9), 256, 0, stream>>>(out1, out2, out3, theta_w, phi_w,
                                                 Wg_w, Th, Ph, Wg);
    // attention windows + pool
    k_stageB<<<dim3(2048), 512, 0, stream>>>(out1, out2, out3, Th, Ph, Wg, W_b, Pl);
    // MLP
    k_gemm_nt_act<<<dim3(32, 8), 256, 0, stream>>>(Pl, p1_w, h1, 2048, 512, 512);
    k_gemm_nt_act<<<dim3(32, 8), 256, 0, stream>>>(h1, p2_w, h2, 2048, 512, 512);
    k_final<<<dim3(512), 256, 0, stream>>>(h2, p3_w, p3_b, outp);
}